// Round 11
// baseline (527.861 us; speedup 1.0000x reference)
//
#include <hip/hip_runtime.h>
#include <math.h>

#define NEGV (-1000.0f)
#define SLOPE 0.01f
#define D_IN 256
#define LDK 72

typedef _Float16 half8 __attribute__((ext_vector_type(8)));
typedef _Float16 half4h __attribute__((ext_vector_type(4)));
typedef float f32x4 __attribute__((ext_vector_type(4)));

__device__ __forceinline__ int rli(int v, int l) {
    return __builtin_amdgcn_readlane(v, l);
}
__device__ __forceinline__ void nt_store2(float* p, float a, float b) {
    float2 v = make_float2(a, b);
    __builtin_nontemporal_store(__builtin_bit_cast(double, v), (double*)p);
}

// ---------- W prep: W[h][k][f] fp32 -> split fp16 Wt_hi/Wt_lo[c][k], c=f*4+h ----------
__global__ void wprep_kernel(const float* __restrict__ W, _Float16* __restrict__ Wt_hi,
                             _Float16* __restrict__ Wt_lo) {
    int i = blockIdx.x * 256 + threadIdx.x;   // 65536, input-coalesced
    int f = i & 63;
    int k = (i >> 6) & 255;
    int h = i >> 14;
    float w = W[i];
    _Float16 hi = (_Float16)w;
    _Float16 lo = (_Float16)(w - (float)hi);
    int c = f * 4 + h;
    Wt_hi[c * 256 + k] = hi;
    Wt_lo[c * 256 + k] = lo;
}

// ---------- Wa prep: wa[q][k] = sum_f W[h][k][f] * att[h][sel*64+f], q = sel*4+h ----------
// (es/ed are linear in z: es = h . (W a_src), so the N x 8 es/ed matrix is a GEMV on hmat)
__global__ void waprep_kernel(const float* __restrict__ W, const float* __restrict__ att,
                              float* __restrict__ wa) {
    int q = blockIdx.x;      // 0..7: (q&3)=head, (q>>2)=0 es / 1 ed
    int k = threadIdx.x;     // 0..255
    int h = q & 3, sel = q >> 2;
    float acc = 0.f;
    for (int f = 0; f < 64; f++)
        acc += W[((size_t)h * 256 + k) * 64 + f] * att[h * 128 + sel * 64 + f];
    wa[q * 256 + k] = acc;
}

// ---------- split-fp16 MFMA GEMM: writes ONLY the fp16 z image, in-row layout ----------
// z image: half index n*512 + 256 + c (bytes [512,1024) of each 1 KB z_t row; the lower
// halves are dead and reused as slot[] scratch by hist). Values are (fp16)acc — bit-
// identical to the r6/r10 path that stored fp32 then converted.
__global__ __launch_bounds__(512) void gemm_kernel(const float* __restrict__ hmat,
        const _Float16* __restrict__ Wt_hi, const _Float16* __restrict__ Wt_lo,
        _Float16* __restrict__ z16, int N) {
    __shared__ __align__(16) _Float16 smem[4 * 128 * LDK];   // 73728 B
    _Float16* A_hi = smem;
    _Float16* A_lo = smem + 128 * LDK;
    _Float16* B_hi = smem + 2 * 128 * LDK;
    _Float16* B_lo = smem + 3 * 128 * LDK;
    const int t = threadIdx.x;
    const int lane = t & 63;
    const int w = t >> 6;
    const int quad = lane >> 4;
    const int m16 = lane & 15;
    const int rg = w & 3;
    const int cg = w >> 2;
    const int n0 = (blockIdx.x >> 1) * 128;
    const int c0 = (blockIdx.x & 1) * 128;

    f32x4 acc[2][4];
#pragma unroll
    for (int rt = 0; rt < 2; rt++)
#pragma unroll
        for (int ct = 0; ct < 4; ct++) acc[rt][ct] = (f32x4){0.f, 0.f, 0.f, 0.f};

    for (int kc = 0; kc < 256; kc += 64) {
        __syncthreads();
        // stage A: 128 rows x 64 k, fp32 -> hi/lo fp16
#pragma unroll
        for (int i = 0; i < 4; i++) {
            int idx = i * 512 + t;                    // 0..2047
            int row = idx >> 4, q = idx & 15;
            int rr = min(n0 + row, N - 1);            // clamp; garbage rows masked at store
            float4 v = *(const float4*)&hmat[(size_t)rr * 256 + kc + q * 4];
            half4h hv, lv;
            hv[0] = (_Float16)v.x; lv[0] = (_Float16)(v.x - (float)hv[0]);
            hv[1] = (_Float16)v.y; lv[1] = (_Float16)(v.y - (float)hv[1]);
            hv[2] = (_Float16)v.z; lv[2] = (_Float16)(v.z - (float)hv[2]);
            hv[3] = (_Float16)v.w; lv[3] = (_Float16)(v.w - (float)hv[3]);
            *(half4h*)&A_hi[row * LDK + q * 4] = hv;
            *(half4h*)&A_lo[row * LDK + q * 4] = lv;
        }
        // stage B: 128 c x 64 k fp16 hi/lo
#pragma unroll
        for (int i = 0; i < 2; i++) {
            int idx = i * 512 + t;                    // 0..1023
            int c = idx >> 3, seg = idx & 7;
            float4 vh = *(const float4*)&Wt_hi[(c0 + c) * 256 + kc + seg * 8];
            float4 vl = *(const float4*)&Wt_lo[(c0 + c) * 256 + kc + seg * 8];
            *(float4*)&B_hi[c * LDK + seg * 8] = vh;
            *(float4*)&B_lo[c * LDK + seg * 8] = vl;
        }
        __syncthreads();
#pragma unroll
        for (int ks = 0; ks < 2; ks++) {
            half8 ah[2], al[2], bh[4], bl[4];
#pragma unroll
            for (int rt = 0; rt < 2; rt++) {
                int ro = ((rg * 2 + rt) * 16 + m16) * LDK + ks * 32 + quad * 8;
                ah[rt] = *(const half8*)&A_hi[ro];
                al[rt] = *(const half8*)&A_lo[ro];
            }
#pragma unroll
            for (int ct = 0; ct < 4; ct++) {
                int co = ((cg * 4 + ct) * 16 + m16) * LDK + ks * 32 + quad * 8;
                bh[ct] = *(const half8*)&B_hi[co];
                bl[ct] = *(const half8*)&B_lo[co];
            }
#pragma unroll
            for (int rt = 0; rt < 2; rt++)
#pragma unroll
                for (int ct = 0; ct < 4; ct++) {
                    acc[rt][ct] = __builtin_amdgcn_mfma_f32_16x16x32_f16(ah[rt], bh[ct], acc[rt][ct], 0, 0, 0);
                    acc[rt][ct] = __builtin_amdgcn_mfma_f32_16x16x32_f16(al[rt], bh[ct], acc[rt][ct], 0, 0, 0);
                    acc[rt][ct] = __builtin_amdgcn_mfma_f32_16x16x32_f16(ah[rt], bl[ct], acc[rt][ct], 0, 0, 0);
                }
        }
    }
    // epilogue: C/D col=lane&15, row=quad*4+reg; fp16 image stores only
#pragma unroll
    for (int rt = 0; rt < 2; rt++)
#pragma unroll
        for (int ct = 0; ct < 4; ct++)
#pragma unroll
            for (int r = 0; r < 4; r++) {
                int n = n0 + rg * 32 + rt * 16 + quad * 4 + r;
                int c = c0 + cg * 64 + ct * 16 + m16;
                if (n < N) z16[(size_t)n * 512 + 256 + c] = (_Float16)acc[rt][ct][r];
            }
}

// ---------- es/ed GEMV: es_ed[n][q] = hmat[n] . wa[q], q = 0..7 ----------
// Wave per node (grid-stride); wa rows cached in registers across nodes. Single writer,
// fixed reduction order -> deterministic.
__global__ __launch_bounds__(256) void esgemv_kernel(const float* __restrict__ hmat,
        const float* __restrict__ wa, float* __restrict__ es_ed, int N) {
    int lane = threadIdx.x & 63;
    int wv0 = (blockIdx.x * blockDim.x + threadIdx.x) >> 6;
    int nw = (gridDim.x * blockDim.x) >> 6;
    float4 w0 = *(const float4*)&wa[0 * 256 + lane * 4];
    float4 w1 = *(const float4*)&wa[1 * 256 + lane * 4];
    float4 w2 = *(const float4*)&wa[2 * 256 + lane * 4];
    float4 w3 = *(const float4*)&wa[3 * 256 + lane * 4];
    float4 w4 = *(const float4*)&wa[4 * 256 + lane * 4];
    float4 w5 = *(const float4*)&wa[5 * 256 + lane * 4];
    float4 w6 = *(const float4*)&wa[6 * 256 + lane * 4];
    float4 w7 = *(const float4*)&wa[7 * 256 + lane * 4];
    for (int n = wv0; n < N; n += nw) {
        float4 hv = *(const float4*)&hmat[(size_t)n * 256 + lane * 4];
        float s0 = hv.x * w0.x + hv.y * w0.y + hv.z * w0.z + hv.w * w0.w;
        float s1 = hv.x * w1.x + hv.y * w1.y + hv.z * w1.z + hv.w * w1.w;
        float s2 = hv.x * w2.x + hv.y * w2.y + hv.z * w2.z + hv.w * w2.w;
        float s3 = hv.x * w3.x + hv.y * w3.y + hv.z * w3.z + hv.w * w3.w;
        float s4 = hv.x * w4.x + hv.y * w4.y + hv.z * w4.z + hv.w * w4.w;
        float s5 = hv.x * w5.x + hv.y * w5.y + hv.z * w5.z + hv.w * w5.w;
        float s6 = hv.x * w6.x + hv.y * w6.y + hv.z * w6.z + hv.w * w6.w;
        float s7 = hv.x * w7.x + hv.y * w7.y + hv.z * w7.z + hv.w * w7.w;
        for (int off = 1; off < 64; off <<= 1) {
            s0 += __shfl_xor(s0, off); s1 += __shfl_xor(s1, off);
            s2 += __shfl_xor(s2, off); s3 += __shfl_xor(s3, off);
            s4 += __shfl_xor(s4, off); s5 += __shfl_xor(s5, off);
            s6 += __shfl_xor(s6, off); s7 += __shfl_xor(s7, off);
        }
        if (lane == 0) {
            *(float4*)&es_ed[(size_t)n * 8]     = make_float4(s0, s1, s2, s3);
            *(float4*)&es_ed[(size_t)n * 8 + 4] = make_float4(s4, s5, s6, s7);
        }
    }
}

// ---------- CSR build ----------
// hist records each edge's within-bucket slot (the atomicAdd return) in the DEAD fp32
// lower halves of z_t rows: slot i at int index (i>>7)*256 + (i&127).
__global__ void hist_kernel(const int* __restrict__ dst, int* __restrict__ counts,
                            int* __restrict__ slot, int E) {
    int i = blockIdx.x * blockDim.x + threadIdx.x;
    if (i < E) {
        int sl = atomicAdd(&counts[dst[i]], 1);
        slot[((i >> 7) << 8) + (i & 127)] = sl;
    }
}

__global__ void scanA_kernel(const int* __restrict__ counts, int* __restrict__ bsums, int N) {
    __shared__ int lds[256];
    int t = threadIdx.x;
    int base = blockIdx.x * 1024 + t * 4;
    int s = 0;
    if (base + 3 < N) {
        int4 v = *(const int4*)&counts[base];
        s = v.x + v.y + v.z + v.w;
    } else {
        for (int u = 0; u < 4; u++) if (base + u < N) s += counts[base + u];
    }
    lds[t] = s; __syncthreads();
    for (int off = 128; off > 0; off >>= 1) {
        if (t < off) lds[t] += lds[t + off];
        __syncthreads();
    }
    if (t == 0) bsums[blockIdx.x] = lds[0];
}

__global__ void scanB_kernel(int* __restrict__ bsums, int nb) {
    __shared__ int lds[256];
    int t = threadIdx.x;
    int v = (t < nb) ? bsums[t] : 0;
    lds[t] = v; __syncthreads();
    for (int off = 1; off < 256; off <<= 1) {
        int x = (t >= off) ? lds[t - off] : 0;
        __syncthreads();
        lds[t] += x;
        __syncthreads();
    }
    if (t < nb) bsums[t] = lds[t] - v;   // exclusive
}

__global__ void scanC_kernel(const int* __restrict__ counts, const int* __restrict__ bsums,
                             int* __restrict__ row_start, int N) {
    __shared__ int lds[256];
    int t = threadIdx.x;
    int base = blockIdx.x * 1024 + t * 4;
    int4 v = make_int4(0, 0, 0, 0);
    if (base + 3 < N) v = *(const int4*)&counts[base];
    else {
        if (base + 0 < N) v.x = counts[base + 0];
        if (base + 1 < N) v.y = counts[base + 1];
        if (base + 2 < N) v.z = counts[base + 2];
    }
    int s = v.x + v.y + v.z + v.w;
    lds[t] = s; __syncthreads();
    for (int off = 1; off < 256; off <<= 1) {
        int x = (t >= off) ? lds[t - off] : 0;
        __syncthreads();
        lds[t] += x;
        __syncthreads();
    }
    int excl = lds[t] - s + bsums[blockIdx.x];
    int4 r;
    r.x = excl; r.y = r.x + v.x; r.z = r.y + v.y; r.w = r.z + v.z;
    if (base + 3 < N) *(int4*)&row_start[base] = r;
    else {
        if (base + 0 < N) row_start[base + 0] = r.x;
        if (base + 1 < N) row_start[base + 1] = r.y;
        if (base + 2 < N) row_start[base + 2] = r.z;
    }
}

__global__ void scatter_kernel(const int* __restrict__ src, const int* __restrict__ dst,
                               const int* __restrict__ row_start, const int* __restrict__ slot,
                               int* __restrict__ csr_src, int E) {
    int i = blockIdx.x * blockDim.x + threadIdx.x;
    if (i < E) {
        int d = dst[i];
        csr_src[row_start[d] + slot[((i >> 7) << 8) + (i & 127)]] = src[i];
    }
}

// ---------- aggregation: TWO nodes per wave (32 lanes each), online softmax ----------
// (unchanged from the passing r10 kernel)
__global__ __launch_bounds__(256) void aggregate_kernel(const _Float16* __restrict__ z16,
        const float* __restrict__ es_ed, const int* __restrict__ csr_src,
        const int* __restrict__ row_start, const int* __restrict__ counts,
        float* __restrict__ out, int N) {
    int gid = blockIdx.x * blockDim.x + threadIdx.x;
    int wv = gid >> 6;
    int lane = gid & 63;
    if (2 * wv >= N) return;              // wave-uniform
    int half = lane >> 5;
    int hl = lane & 31;
    int n = 2 * wv + half;
    int nn = min(n, N - 1);               // clamp for odd tails; store masked
    int cnt = counts[nn];
    int start = row_start[nn];
    float4 edn = *(const float4*)&es_ed[(size_t)nn * 8 + 4];
    int cmax = max(rli(cnt, 0), rli(cnt, 32));
    int hb = half << 5;

    float m0 = -INFINITY, m1 = -INFINITY, m2 = -INFINITY, m3 = -INFINITY;
    float l0 = 0.f, l1 = 0.f, l2 = 0.f, l3 = 0.f;
    float o0 = 0.f, o1 = 0.f, o2 = 0.f, o3 = 0.f;
    float o4 = 0.f, o5 = 0.f, o6 = 0.f, o7 = 0.f;

    for (int base = 0; base < cmax; base += 32) {
        int i = base + hl;
        int s = 0;
        float e0 = -INFINITY, e1 = -INFINITY, e2 = -INFINITY, e3 = -INFINITY;
        if (i < cnt) {
            s = csr_src[start + i];
            float4 esv = *(const float4*)&es_ed[(size_t)s * 8];
            float x0 = esv.x + edn.x; e0 = x0 > 0.f ? x0 : SLOPE * x0; if (e0 == 0.f) e0 = NEGV;
            float x1 = esv.y + edn.y; e1 = x1 > 0.f ? x1 : SLOPE * x1; if (e1 == 0.f) e1 = NEGV;
            float x2 = esv.z + edn.z; e2 = x2 > 0.f ? x2 : SLOPE * x2; if (e2 == 0.f) e2 = NEGV;
            float x3 = esv.w + edn.w; e3 = x3 > 0.f ? x3 : SLOPE * x3; if (e3 == 0.f) e3 = NEGV;
        }
        float c0 = e0, c1 = e1, c2 = e2, c3 = e3;
#pragma unroll
        for (int off = 1; off < 32; off <<= 1) {
            c0 = fmaxf(c0, __shfl_xor(c0, off)); c1 = fmaxf(c1, __shfl_xor(c1, off));
            c2 = fmaxf(c2, __shfl_xor(c2, off)); c3 = fmaxf(c3, __shfl_xor(c3, off));
        }
        float nm0 = fmaxf(m0, c0), nm1 = fmaxf(m1, c1), nm2 = fmaxf(m2, c2), nm3 = fmaxf(m3, c3);
        float sc0 = __expf(m0 - nm0), sc1 = __expf(m1 - nm1);
        float sc2 = __expf(m2 - nm2), sc3 = __expf(m3 - nm3);
        o0 *= sc0; o1 *= sc1; o2 *= sc2; o3 *= sc3;
        o4 *= sc0; o5 *= sc1; o6 *= sc2; o7 *= sc3;
        l0 *= sc0; l1 *= sc1; l2 *= sc2; l3 *= sc3;
        m0 = nm0; m1 = nm1; m2 = nm2; m3 = nm3;

        float p0 = 0.f, p1 = 0.f, p2 = 0.f, p3 = 0.f;
        if (i < cnt) {
            p0 = __expf(e0 - m0); p1 = __expf(e1 - m1);
            p2 = __expf(e2 - m2); p3 = __expf(e3 - m3);
        }
        l0 += p0; l1 += p1; l2 += p2; l3 += p3;

        int jmax = min(32, cmax - base);
        int j = 0;
        for (; j + 7 < jmax; j += 8) {
            half8 zz[8]; float4 qq[8];
#pragma unroll
            for (int u = 0; u < 8; u++) {
                int idx = hb + j + u;             // uniform within each half
                int ss = __shfl(s, idx);
                qq[u] = make_float4(__shfl(p0, idx), __shfl(p1, idx),
                                    __shfl(p2, idx), __shfl(p3, idx));
                zz[u] = *(const half8*)&z16[(size_t)ss * 512 + 256 + hl * 8];
            }
#pragma unroll
            for (int u = 0; u < 8; u++) {
                o0 += qq[u].x * (float)zz[u][0]; o1 += qq[u].y * (float)zz[u][1];
                o2 += qq[u].z * (float)zz[u][2]; o3 += qq[u].w * (float)zz[u][3];
                o4 += qq[u].x * (float)zz[u][4]; o5 += qq[u].y * (float)zz[u][5];
                o6 += qq[u].z * (float)zz[u][6]; o7 += qq[u].w * (float)zz[u][7];
            }
        }
        for (; j < jmax; ++j) {
            int idx = hb + j;
            int ss = __shfl(s, idx);
            float q0 = __shfl(p0, idx), q1 = __shfl(p1, idx);
            float q2 = __shfl(p2, idx), q3 = __shfl(p3, idx);
            half8 zv = *(const half8*)&z16[(size_t)ss * 512 + 256 + hl * 8];
            o0 += q0 * (float)zv[0]; o1 += q1 * (float)zv[1];
            o2 += q2 * (float)zv[2]; o3 += q3 * (float)zv[3];
            o4 += q0 * (float)zv[4]; o5 += q1 * (float)zv[5];
            o6 += q2 * (float)zv[6]; o7 += q3 * (float)zv[7];
        }
    }
#pragma unroll
    for (int off = 1; off < 32; off <<= 1) {
        l0 += __shfl_xor(l0, off); l1 += __shfl_xor(l1, off);
        l2 += __shfl_xor(l2, off); l3 += __shfl_xor(l3, off);
    }
    if (n < N) {
        if (cnt > 0) {
            o0 /= l0; o1 /= l1; o2 /= l2; o3 /= l3;
            o4 /= l0; o5 /= l1; o6 /= l2; o7 /= l3;
        }
        float* ob = &out[(size_t)n * 256 + 2 * hl];
        nt_store2(ob + 0,   o0, o4);
        nt_store2(ob + 64,  o1, o5);
        nt_store2(ob + 128, o2, o6);
        nt_store2(ob + 192, o3, o7);
    }
}

extern "C" void kernel_launch(void* const* d_in, const int* in_sizes, int n_in,
                              void* d_out, int out_size, void* d_ws, size_t ws_size,
                              hipStream_t stream) {
    const float* hmat = (const float*)d_in[0];
    const float* W    = (const float*)d_in[1];
    const float* att  = (const float*)d_in[2];
    const int*   src  = (const int*)d_in[3];
    const int*   dst  = (const int*)d_in[4];
    int N = in_sizes[0] / D_IN;
    int E = in_sizes[3];
    float* out = (float*)d_out;

    // workspace layout (16B-aligned); identical footprint to the proven r10 layout
    float* z_t      = (float*)d_ws;                       // N*256 fp32 region: fp16 image
                                                          // in upper row halves; slot[] in
                                                          // lower halves
    float* es_ed    = z_t + (size_t)N * 256;              // N*8
    _Float16* Wt_hi = (_Float16*)(es_ed + (size_t)N * 8); // 65536 fp16
    _Float16* Wt_lo = Wt_hi + 65536;                      // 65536 fp16
    int*   counts   = (int*)(Wt_lo + 65536);              // N
    int*   cursor   = counts + N;                         // N (dead; wa lives here)
    int*   row_start= cursor + N;                         // N
    int*   bsums    = row_start + N;                      // <=256
    int*   csr_src  = bsums + 256;                        // E
    int*   slot     = (int*)z_t;                          // strided into dead row halves
    float* wa       = (float*)cursor;                     // 8*256 fp32 (within dead cursor)

    int NB = (N + 1023) / 1024;
    int aggBlocks = ((N + 1) / 2 + 3) / 4;                // 2 nodes/wave, 4 waves/block

    hipMemsetAsync(counts, 0, (size_t)N * sizeof(int), stream);
    wprep_kernel<<<256, 256, 0, stream>>>(W, Wt_hi, Wt_lo);
    waprep_kernel<<<8, 256, 0, stream>>>(W, att, wa);
    gemm_kernel<<<((N + 127) / 128) * 2, 512, 0, stream>>>(hmat, Wt_hi, Wt_lo, (_Float16*)z_t, N);
    esgemv_kernel<<<2048, 256, 0, stream>>>(hmat, wa, es_ed, N);
    hist_kernel<<<(E + 255) / 256, 256, 0, stream>>>(dst, counts, slot, E);
    scanA_kernel<<<NB, 256, 0, stream>>>(counts, bsums, N);
    scanB_kernel<<<1, 256, 0, stream>>>(bsums, NB);
    scanC_kernel<<<NB, 256, 0, stream>>>(counts, bsums, row_start, N);
    scatter_kernel<<<(E + 255) / 256, 256, 0, stream>>>(src, dst, row_start, slot, csr_src, E);
    aggregate_kernel<<<aggBlocks, 256, 0, stream>>>((const _Float16*)z_t, es_ed, csr_src, row_start, counts, out, N);
}

// Round 12
// 527.016 us; speedup vs baseline: 1.0016x; 1.0016x over previous
//
#include <hip/hip_runtime.h>
#include <math.h>

#define NEGV (-1000.0f)
#define SLOPE 0.01f
#define D_IN 256
#define LDK 72

typedef _Float16 half8 __attribute__((ext_vector_type(8)));
typedef _Float16 half4h __attribute__((ext_vector_type(4)));
typedef float f32x4 __attribute__((ext_vector_type(4)));

__device__ __forceinline__ int rli(int v, int l) {
    return __builtin_amdgcn_readlane(v, l);
}
__device__ __forceinline__ void nt_store2(float* p, float a, float b) {
    float2 v = make_float2(a, b);
    __builtin_nontemporal_store(__builtin_bit_cast(double, v), (double*)p);
}

// ---------- W prep: W[h][k][f] fp32 -> split fp16 Wt_hi/Wt_lo[c][k], c=f*4+h ----------
__global__ void wprep_kernel(const float* __restrict__ W, _Float16* __restrict__ Wt_hi,
                             _Float16* __restrict__ Wt_lo) {
    int i = blockIdx.x * 256 + threadIdx.x;   // 65536, input-coalesced
    int f = i & 63;
    int k = (i >> 6) & 255;
    int h = i >> 14;
    float w = W[i];
    _Float16 hi = (_Float16)w;
    _Float16 lo = (_Float16)(w - (float)hi);
    int c = f * 4 + h;
    Wt_hi[c * 256 + k] = hi;
    Wt_lo[c * 256 + k] = lo;
}

// ---------- split-fp16 MFMA GEMM: z_t[n][c] = sum_k h[n][k]*Wt[c][k], fp32 out ----------
// (byte-identical to the proven r0/r10 GEMM)
__global__ __launch_bounds__(512) void gemm_kernel(const float* __restrict__ hmat,
        const _Float16* __restrict__ Wt_hi, const _Float16* __restrict__ Wt_lo,
        float* __restrict__ z_t, int N) {
    __shared__ __align__(16) _Float16 smem[4 * 128 * LDK];   // 73728 B
    _Float16* A_hi = smem;
    _Float16* A_lo = smem + 128 * LDK;
    _Float16* B_hi = smem + 2 * 128 * LDK;
    _Float16* B_lo = smem + 3 * 128 * LDK;
    const int t = threadIdx.x;
    const int lane = t & 63;
    const int w = t >> 6;
    const int quad = lane >> 4;
    const int m16 = lane & 15;
    const int rg = w & 3;
    const int cg = w >> 2;
    const int n0 = (blockIdx.x >> 1) * 128;
    const int c0 = (blockIdx.x & 1) * 128;

    f32x4 acc[2][4];
#pragma unroll
    for (int rt = 0; rt < 2; rt++)
#pragma unroll
        for (int ct = 0; ct < 4; ct++) acc[rt][ct] = (f32x4){0.f, 0.f, 0.f, 0.f};

    for (int kc = 0; kc < 256; kc += 64) {
        __syncthreads();
        // stage A: 128 rows x 64 k, fp32 -> hi/lo fp16
#pragma unroll
        for (int i = 0; i < 4; i++) {
            int idx = i * 512 + t;                    // 0..2047
            int row = idx >> 4, q = idx & 15;
            int rr = min(n0 + row, N - 1);            // clamp; garbage rows masked at store
            float4 v = *(const float4*)&hmat[(size_t)rr * 256 + kc + q * 4];
            half4h hv, lv;
            hv[0] = (_Float16)v.x; lv[0] = (_Float16)(v.x - (float)hv[0]);
            hv[1] = (_Float16)v.y; lv[1] = (_Float16)(v.y - (float)hv[1]);
            hv[2] = (_Float16)v.z; lv[2] = (_Float16)(v.z - (float)hv[2]);
            hv[3] = (_Float16)v.w; lv[3] = (_Float16)(v.w - (float)hv[3]);
            *(half4h*)&A_hi[row * LDK + q * 4] = hv;
            *(half4h*)&A_lo[row * LDK + q * 4] = lv;
        }
        // stage B: 128 c x 64 k fp16 hi/lo
#pragma unroll
        for (int i = 0; i < 2; i++) {
            int idx = i * 512 + t;                    // 0..1023
            int c = idx >> 3, seg = idx & 7;
            float4 vh = *(const float4*)&Wt_hi[(c0 + c) * 256 + kc + seg * 8];
            float4 vl = *(const float4*)&Wt_lo[(c0 + c) * 256 + kc + seg * 8];
            *(float4*)&B_hi[c * LDK + seg * 8] = vh;
            *(float4*)&B_lo[c * LDK + seg * 8] = vl;
        }
        __syncthreads();
#pragma unroll
        for (int ks = 0; ks < 2; ks++) {
            half8 ah[2], al[2], bh[4], bl[4];
#pragma unroll
            for (int rt = 0; rt < 2; rt++) {
                int ro = ((rg * 2 + rt) * 16 + m16) * LDK + ks * 32 + quad * 8;
                ah[rt] = *(const half8*)&A_hi[ro];
                al[rt] = *(const half8*)&A_lo[ro];
            }
#pragma unroll
            for (int ct = 0; ct < 4; ct++) {
                int co = ((cg * 4 + ct) * 16 + m16) * LDK + ks * 32 + quad * 8;
                bh[ct] = *(const half8*)&B_hi[co];
                bl[ct] = *(const half8*)&B_lo[co];
            }
#pragma unroll
            for (int rt = 0; rt < 2; rt++)
#pragma unroll
                for (int ct = 0; ct < 4; ct++) {
                    acc[rt][ct] = __builtin_amdgcn_mfma_f32_16x16x32_f16(ah[rt], bh[ct], acc[rt][ct], 0, 0, 0);
                    acc[rt][ct] = __builtin_amdgcn_mfma_f32_16x16x32_f16(al[rt], bh[ct], acc[rt][ct], 0, 0, 0);
                    acc[rt][ct] = __builtin_amdgcn_mfma_f32_16x16x32_f16(ah[rt], bl[ct], acc[rt][ct], 0, 0, 0);
                }
        }
    }
    // epilogue: C/D col=lane&15, row=quad*4+reg; direct fp32 stores (16-lane coalesced)
#pragma unroll
    for (int rt = 0; rt < 2; rt++)
#pragma unroll
        for (int ct = 0; ct < 4; ct++)
#pragma unroll
            for (int r = 0; r < 4; r++) {
                int n = n0 + rg * 32 + rt * 16 + quad * 4 + r;
                int c = c0 + cg * 64 + ct * 16 + m16;
                if (n < N) z_t[(size_t)n * 256 + c] = acc[rt][ct][r];
            }
}

// ---------- es/ed per node (fp32 z) + in-row fp16 z image for the aggregation ----------
__global__ void esed_kernel(float* __restrict__ z_t, const float* __restrict__ att,
                            float* __restrict__ es_ed, int N) {
    int gid = blockIdx.x * blockDim.x + threadIdx.x;
    int n = gid >> 6;
    int lane = gid & 63;
    if (n >= N) return;
    float4 zv = *(const float4*)&z_t[(size_t)n * 256 + lane * 4];
    float ps0 = zv.x * att[0 * 128 + lane];
    float ps1 = zv.y * att[1 * 128 + lane];
    float ps2 = zv.z * att[2 * 128 + lane];
    float ps3 = zv.w * att[3 * 128 + lane];
    float pd0 = zv.x * att[0 * 128 + 64 + lane];
    float pd1 = zv.y * att[1 * 128 + 64 + lane];
    float pd2 = zv.z * att[2 * 128 + 64 + lane];
    float pd3 = zv.w * att[3 * 128 + 64 + lane];
    for (int off = 1; off < 64; off <<= 1) {
        ps0 += __shfl_xor(ps0, off); ps1 += __shfl_xor(ps1, off);
        ps2 += __shfl_xor(ps2, off); ps3 += __shfl_xor(ps3, off);
        pd0 += __shfl_xor(pd0, off); pd1 += __shfl_xor(pd1, off);
        pd2 += __shfl_xor(pd2, off); pd3 += __shfl_xor(pd3, off);
    }
    // fp16 image: half index n*512 + 256 + lane*4  (= byte n*1024 + 512 + lane*8)
    half4h h16;
    h16[0] = (_Float16)zv.x; h16[1] = (_Float16)zv.y;
    h16[2] = (_Float16)zv.z; h16[3] = (_Float16)zv.w;
    *(half4h*)((_Float16*)z_t + (size_t)n * 512 + 256 + lane * 4) = h16;
    if (lane == 0) {
        *(float4*)&es_ed[(size_t)n * 8]     = make_float4(ps0, ps1, ps2, ps3);
        *(float4*)&es_ed[(size_t)n * 8 + 4] = make_float4(pd0, pd1, pd2, pd3);
    }
}

// ---------- CSR build ----------
// hist records each edge's within-bucket slot (the atomicAdd return) in the DEAD fp32
// lower halves of z_t rows: slot i at int index (i>>7)*256 + (i&127).
__global__ void hist_kernel(const int* __restrict__ dst, int* __restrict__ counts,
                            int* __restrict__ slot, int E) {
    int i = blockIdx.x * blockDim.x + threadIdx.x;
    if (i < E) {
        int sl = atomicAdd(&counts[dst[i]], 1);
        slot[((i >> 7) << 8) + (i & 127)] = sl;
    }
}

__global__ void scanA_kernel(const int* __restrict__ counts, int* __restrict__ bsums, int N) {
    __shared__ int lds[256];
    int t = threadIdx.x;
    int base = blockIdx.x * 1024 + t * 4;
    int s = 0;
    if (base + 3 < N) {
        int4 v = *(const int4*)&counts[base];
        s = v.x + v.y + v.z + v.w;
    } else {
        for (int u = 0; u < 4; u++) if (base + u < N) s += counts[base + u];
    }
    lds[t] = s; __syncthreads();
    for (int off = 128; off > 0; off >>= 1) {
        if (t < off) lds[t] += lds[t + off];
        __syncthreads();
    }
    if (t == 0) bsums[blockIdx.x] = lds[0];
}

__global__ void scanB_kernel(int* __restrict__ bsums, int nb) {
    __shared__ int lds[256];
    int t = threadIdx.x;
    int v = (t < nb) ? bsums[t] : 0;
    lds[t] = v; __syncthreads();
    for (int off = 1; off < 256; off <<= 1) {
        int x = (t >= off) ? lds[t - off] : 0;
        __syncthreads();
        lds[t] += x;
        __syncthreads();
    }
    if (t < nb) bsums[t] = lds[t] - v;   // exclusive
}

__global__ void scanC_kernel(const int* __restrict__ counts, const int* __restrict__ bsums,
                             int* __restrict__ row_start, int N) {
    __shared__ int lds[256];
    int t = threadIdx.x;
    int base = blockIdx.x * 1024 + t * 4;
    int4 v = make_int4(0, 0, 0, 0);
    if (base + 3 < N) v = *(const int4*)&counts[base];
    else {
        if (base + 0 < N) v.x = counts[base + 0];
        if (base + 1 < N) v.y = counts[base + 1];
        if (base + 2 < N) v.z = counts[base + 2];
    }
    int s = v.x + v.y + v.z + v.w;
    lds[t] = s; __syncthreads();
    for (int off = 1; off < 256; off <<= 1) {
        int x = (t >= off) ? lds[t - off] : 0;
        __syncthreads();
        lds[t] += x;
        __syncthreads();
    }
    int excl = lds[t] - s + bsums[blockIdx.x];
    int4 r;
    r.x = excl; r.y = r.x + v.x; r.z = r.y + v.y; r.w = r.z + v.z;
    if (base + 3 < N) *(int4*)&row_start[base] = r;
    else {
        if (base + 0 < N) row_start[base + 0] = r.x;
        if (base + 1 < N) row_start[base + 1] = r.y;
        if (base + 2 < N) row_start[base + 2] = r.z;
    }
}

__global__ void scatter_kernel(const int* __restrict__ src, const int* __restrict__ dst,
                               const int* __restrict__ row_start, const int* __restrict__ slot,
                               int* __restrict__ csr_src, int E) {
    int i = blockIdx.x * blockDim.x + threadIdx.x;
    if (i < E) {
        int d = dst[i];
        csr_src[row_start[d] + slot[((i >> 7) << 8) + (i & 127)]] = src[i];
    }
}

// ---------- aggregation: TWO nodes per wave (32 lanes each), online softmax ----------
// Same per-wave code as the passing r10 kernel; launched as 1024-thread blocks
// (16 waves/block) to raise resident waves/CU past the ~12-wave plateau seen with
// 4-wave blocks. No __syncthreads; indexing is global-id based, so geometry-safe.
__global__ __launch_bounds__(1024) void aggregate_kernel(const _Float16* __restrict__ z16,
        const float* __restrict__ es_ed, const int* __restrict__ csr_src,
        const int* __restrict__ row_start, const int* __restrict__ counts,
        float* __restrict__ out, int N) {
    int gid = blockIdx.x * blockDim.x + threadIdx.x;
    int wv = gid >> 6;
    int lane = gid & 63;
    if (2 * wv >= N) return;              // wave-uniform
    int half = lane >> 5;
    int hl = lane & 31;
    int n = 2 * wv + half;
    int nn = min(n, N - 1);               // clamp for odd tails; store masked
    int cnt = counts[nn];
    int start = row_start[nn];
    float4 edn = *(const float4*)&es_ed[(size_t)nn * 8 + 4];
    int cmax = max(rli(cnt, 0), rli(cnt, 32));
    int hb = half << 5;

    float m0 = -INFINITY, m1 = -INFINITY, m2 = -INFINITY, m3 = -INFINITY;
    float l0 = 0.f, l1 = 0.f, l2 = 0.f, l3 = 0.f;
    float o0 = 0.f, o1 = 0.f, o2 = 0.f, o3 = 0.f;
    float o4 = 0.f, o5 = 0.f, o6 = 0.f, o7 = 0.f;

    for (int base = 0; base < cmax; base += 32) {
        int i = base + hl;
        int s = 0;
        float e0 = -INFINITY, e1 = -INFINITY, e2 = -INFINITY, e3 = -INFINITY;
        if (i < cnt) {
            s = csr_src[start + i];
            float4 esv = *(const float4*)&es_ed[(size_t)s * 8];
            float x0 = esv.x + edn.x; e0 = x0 > 0.f ? x0 : SLOPE * x0; if (e0 == 0.f) e0 = NEGV;
            float x1 = esv.y + edn.y; e1 = x1 > 0.f ? x1 : SLOPE * x1; if (e1 == 0.f) e1 = NEGV;
            float x2 = esv.z + edn.z; e2 = x2 > 0.f ? x2 : SLOPE * x2; if (e2 == 0.f) e2 = NEGV;
            float x3 = esv.w + edn.w; e3 = x3 > 0.f ? x3 : SLOPE * x3; if (e3 == 0.f) e3 = NEGV;
        }
        float c0 = e0, c1 = e1, c2 = e2, c3 = e3;
#pragma unroll
        for (int off = 1; off < 32; off <<= 1) {
            c0 = fmaxf(c0, __shfl_xor(c0, off)); c1 = fmaxf(c1, __shfl_xor(c1, off));
            c2 = fmaxf(c2, __shfl_xor(c2, off)); c3 = fmaxf(c3, __shfl_xor(c3, off));
        }
        float nm0 = fmaxf(m0, c0), nm1 = fmaxf(m1, c1), nm2 = fmaxf(m2, c2), nm3 = fmaxf(m3, c3);
        float sc0 = __expf(m0 - nm0), sc1 = __expf(m1 - nm1);
        float sc2 = __expf(m2 - nm2), sc3 = __expf(m3 - nm3);
        o0 *= sc0; o1 *= sc1; o2 *= sc2; o3 *= sc3;
        o4 *= sc0; o5 *= sc1; o6 *= sc2; o7 *= sc3;
        l0 *= sc0; l1 *= sc1; l2 *= sc2; l3 *= sc3;
        m0 = nm0; m1 = nm1; m2 = nm2; m3 = nm3;

        float p0 = 0.f, p1 = 0.f, p2 = 0.f, p3 = 0.f;
        if (i < cnt) {
            p0 = __expf(e0 - m0); p1 = __expf(e1 - m1);
            p2 = __expf(e2 - m2); p3 = __expf(e3 - m3);
        }
        l0 += p0; l1 += p1; l2 += p2; l3 += p3;

        int jmax = min(32, cmax - base);
        int j = 0;
        for (; j + 7 < jmax; j += 8) {
            half8 zz[8]; float4 qq[8];
#pragma unroll
            for (int u = 0; u < 8; u++) {
                int idx = hb + j + u;             // uniform within each half
                int ss = __shfl(s, idx);
                qq[u] = make_float4(__shfl(p0, idx), __shfl(p1, idx),
                                    __shfl(p2, idx), __shfl(p3, idx));
                zz[u] = *(const half8*)&z16[(size_t)ss * 512 + 256 + hl * 8];
            }
#pragma unroll
            for (int u = 0; u < 8; u++) {
                o0 += qq[u].x * (float)zz[u][0]; o1 += qq[u].y * (float)zz[u][1];
                o2 += qq[u].z * (float)zz[u][2]; o3 += qq[u].w * (float)zz[u][3];
                o4 += qq[u].x * (float)zz[u][4]; o5 += qq[u].y * (float)zz[u][5];
                o6 += qq[u].z * (float)zz[u][6]; o7 += qq[u].w * (float)zz[u][7];
            }
        }
        for (; j < jmax; ++j) {
            int idx = hb + j;
            int ss = __shfl(s, idx);
            float q0 = __shfl(p0, idx), q1 = __shfl(p1, idx);
            float q2 = __shfl(p2, idx), q3 = __shfl(p3, idx);
            half8 zv = *(const half8*)&z16[(size_t)ss * 512 + 256 + hl * 8];
            o0 += q0 * (float)zv[0]; o1 += q1 * (float)zv[1];
            o2 += q2 * (float)zv[2]; o3 += q3 * (float)zv[3];
            o4 += q0 * (float)zv[4]; o5 += q1 * (float)zv[5];
            o6 += q2 * (float)zv[6]; o7 += q3 * (float)zv[7];
        }
    }
#pragma unroll
    for (int off = 1; off < 32; off <<= 1) {
        l0 += __shfl_xor(l0, off); l1 += __shfl_xor(l1, off);
        l2 += __shfl_xor(l2, off); l3 += __shfl_xor(l3, off);
    }
    if (n < N) {
        if (cnt > 0) {
            o0 /= l0; o1 /= l1; o2 /= l2; o3 /= l3;
            o4 /= l0; o5 /= l1; o6 /= l2; o7 /= l3;
        }
        float* ob = &out[(size_t)n * 256 + 2 * hl];
        nt_store2(ob + 0,   o0, o4);
        nt_store2(ob + 64,  o1, o5);
        nt_store2(ob + 128, o2, o6);
        nt_store2(ob + 192, o3, o7);
    }
}

extern "C" void kernel_launch(void* const* d_in, const int* in_sizes, int n_in,
                              void* d_out, int out_size, void* d_ws, size_t ws_size,
                              hipStream_t stream) {
    const float* hmat = (const float*)d_in[0];
    const float* W    = (const float*)d_in[1];
    const float* att  = (const float*)d_in[2];
    const int*   src  = (const int*)d_in[3];
    const int*   dst  = (const int*)d_in[4];
    int N = in_sizes[0] / D_IN;
    int E = in_sizes[3];
    float* out = (float*)d_out;

    // workspace layout (16B-aligned); identical to the proven r10 layout, ~113.5 MB
    float* z_t      = (float*)d_ws;                       // N*256 fp32 (fp16 image in-row;
                                                          // lower halves reused for slot[])
    float* es_ed    = z_t + (size_t)N * 256;              // N*8
    _Float16* Wt_hi = (_Float16*)(es_ed + (size_t)N * 8); // 65536 fp16
    _Float16* Wt_lo = Wt_hi + 65536;                      // 65536 fp16
    int*   counts   = (int*)(Wt_lo + 65536);              // N
    int*   cursor   = counts + N;                         // N (unused; layout kept)
    int*   row_start= cursor + N;                         // N
    int*   bsums    = row_start + N;                      // <=256
    int*   csr_src  = bsums + 256;                        // E
    int*   slot     = (int*)z_t;                          // strided into dead row halves

    int NB = (N + 1023) / 1024;
    int aggBlocks = ((N + 1) / 2 + 15) / 16;              // 2 nodes/wave, 16 waves/block

    hipMemsetAsync(counts, 0, (size_t)N * sizeof(int), stream);
    wprep_kernel<<<256, 256, 0, stream>>>(W, Wt_hi, Wt_lo);
    gemm_kernel<<<((N + 127) / 128) * 2, 512, 0, stream>>>(hmat, Wt_hi, Wt_lo, z_t, N);
    esed_kernel<<<(N * 64 + 255) / 256, 256, 0, stream>>>(z_t, att, es_ed, N);
    hist_kernel<<<(E + 255) / 256, 256, 0, stream>>>(dst, counts, slot, E);
    scanA_kernel<<<NB, 256, 0, stream>>>(counts, bsums, N);
    scanB_kernel<<<1, 256, 0, stream>>>(bsums, NB);
    scanC_kernel<<<NB, 256, 0, stream>>>(counts, bsums, row_start, N);
    scatter_kernel<<<(E + 255) / 256, 256, 0, stream>>>(src, dst, row_start, slot, csr_src, E);
    aggregate_kernel<<<aggBlocks, 1024, 0, stream>>>((const _Float16*)z_t, es_ed, csr_src, row_start, counts, out, N);
}